// Round 1
// baseline (125.818 us; speedup 1.0000x reference)
//
#include <hip/hip_runtime.h>
#include <math.h>

#define NQ 19
#define NL 3
#define NSTATE (1 << NQ)
#define TPB 256
#define CHUNK 2048      // amplitudes per block tile
#define NBLK 256        // tiles per pass
#define PI_F 3.14159265358979323846f

__device__ __forceinline__ float2 cmul(float2 a, float2 b) {
    return make_float2(a.x * b.x - a.y * b.y, a.x * b.y + a.y * b.x);
}
__device__ __forceinline__ float2 cadd(float2 a, float2 b) {
    return make_float2(a.x + b.x, a.y + b.y);
}

// Fused U = RZ(tz) * RY(ty) * RX(tx) for qubit q at layer l.
// Writes u00,u01,u10,u11 into U[0..3].
__device__ void make_U(const float* inputs, const float* yw, const float* zw,
                       int l, int q, bool useRZ, float2* U) {
    float x = inputs[q];
    float ax;
    if (q >= NQ - 2) {
        // directional feature: snap to {0, pi}
        ax = (x >= 0.5f) ? PI_F : 0.0f;
    } else {
        // scale [-1.5,1.5] -> [0, 2pi], clip
        ax = (x + 1.5f) * (2.0f * PI_F / 3.0f);
        ax = fminf(fmaxf(ax, 0.0f), 2.0f * PI_F);
    }
    float ty = yw[l * NQ + q];
    float tz = useRZ ? zw[l * NQ + q] : 0.0f;
    float cx = cosf(0.5f * ax), sx = sinf(0.5f * ax);
    float cy = cosf(0.5f * ty), sy = sinf(0.5f * ty);
    float cz = cosf(0.5f * tz), sz = sinf(0.5f * tz);
    // RY*RX:
    // [ cy*cx + i*sy*sx    -sy*cx - i*cy*sx ]
    // [ sy*cx - i*cy*sx     cy*cx - i*sy*sx ]
    float2 m00 = make_float2(cy * cx, sy * sx);
    float2 m01 = make_float2(-sy * cx, -cy * sx);
    float2 m10 = make_float2(sy * cx, -cy * sx);
    float2 m11 = make_float2(cy * cx, -sy * sx);
    // RZ rows: row0 *= e^{-i tz/2}, row1 *= e^{+i tz/2}
    float2 e0 = make_float2(cz, -sz);
    float2 e1 = make_float2(cz, sz);
    U[0] = cmul(e0, m00);
    U[1] = cmul(e0, m01);
    U[2] = cmul(e1, m10);
    U[3] = cmul(e1, m11);
}

// Pass A: bits 0..10 local (contiguous 2048-amp chunk). Applies fused gates for
// bit positions 0..10 (qubits 18..8). layer==0 synthesizes |0..0> instead of load.
__global__ __launch_bounds__(TPB) void passA(const float* __restrict__ inputs,
                                             const float* __restrict__ yw,
                                             const float* __restrict__ zw,
                                             float2* __restrict__ state,
                                             int layer) {
    __shared__ float2 amp[CHUNK];
    __shared__ float2 U[11][4];
    const int t = threadIdx.x;
    const int c = blockIdx.x;

    if (t < 11) {
        int p = t;              // bit position
        int q = NQ - 1 - p;     // qubit index (bit 18 == qubit 0)
        make_U(inputs, yw, zw, layer, q, /*useRZ=*/(layer != NL - 1), &U[p][0]);
    }

    if (layer == 0) {
        for (int i = t; i < CHUNK; i += TPB) amp[i] = make_float2(0.f, 0.f);
        if (c == 0 && t == 0) amp[0] = make_float2(1.f, 0.f);
    } else {
        const float2* g = state + (size_t)c * CHUNK;
        for (int i = t; i < CHUNK; i += TPB) amp[i] = g[i];
    }
    __syncthreads();

    for (int b = 0; b < 11; ++b) {
        const float2 u00 = U[b][0], u01 = U[b][1], u10 = U[b][2], u11 = U[b][3];
        for (int pp = t; pp < CHUNK / 2; pp += TPB) {
            int i0 = ((pp >> b) << (b + 1)) | (pp & ((1 << b) - 1));
            int i1 = i0 | (1 << b);
            float2 a0 = amp[i0], a1 = amp[i1];
            float2 n0 = cadd(cmul(u00, a0), cmul(u01, a1));
            float2 n1 = cadd(cmul(u10, a0), cmul(u11, a1));
            amp[i0] = n0;
            amp[i1] = n1;
        }
        __syncthreads();
    }

    float2* g = state + (size_t)c * CHUNK;
    for (int i = t; i < CHUNK; i += TPB) g[i] = amp[i];
}

// Pass B: bits 11..18 and bits 0..2 local; bits 3..10 fixed per tile (blockIdx).
// Applies fused gates for bit positions 11..18 (qubits 7..0).
// layer < NL-1: applies the full CZ-ring diagonal sign on store.
// layer == NL-1: computes probs + 8 per-block expval partials (no state store).
__global__ __launch_bounds__(TPB) void passB(const float* __restrict__ inputs,
                                             const float* __restrict__ yw,
                                             const float* __restrict__ zw,
                                             float2* __restrict__ state,
                                             float* __restrict__ partials,
                                             int layer) {
    __shared__ float2 amp[CHUNK];
    __shared__ float2 U[8][4];
    __shared__ float red[32];
    const int t = threadIdx.x;
    const int T = blockIdx.x;   // bits 3..10

    if (t < 8) {
        int p = 11 + t;         // bit position
        int q = NQ - 1 - p;     // qubits 7..0
        make_U(inputs, yw, zw, layer, q, /*useRZ=*/(layer != NL - 1), &U[t][0]);
    }

    // local index li = h*8 + lo  ->  global x = (h<<11) | (T<<3) | lo
    for (int li = t; li < CHUNK; li += TPB) {
        int h = li >> 3, lo = li & 7;
        int x = (h << 11) | (T << 3) | lo;
        amp[li] = state[x];
    }
    __syncthreads();

    for (int j = 0; j < 8; ++j) {
        const int b = 3 + j;    // local bit == global bit 11+j
        const float2 u00 = U[j][0], u01 = U[j][1], u10 = U[j][2], u11 = U[j][3];
        for (int pp = t; pp < CHUNK / 2; pp += TPB) {
            int i0 = ((pp >> b) << (b + 1)) | (pp & ((1 << b) - 1));
            int i1 = i0 | (1 << b);
            float2 a0 = amp[i0], a1 = amp[i1];
            float2 n0 = cadd(cmul(u00, a0), cmul(u01, a1));
            float2 n1 = cadd(cmul(u10, a0), cmul(u11, a1));
            amp[i0] = n0;
            amp[i1] = n1;
        }
        __syncthreads();
    }

    if (layer < NL - 1) {
        // CZ ring diagonal: parity of adjacent-bit products (bits (b,b+1), b=0..17)
        // plus the wrap pair (bits 18,0). Sign flip where parity odd.
        for (int li = t; li < CHUNK; li += TPB) {
            int h = li >> 3, lo = li & 7;
            int x = (h << 11) | (T << 3) | lo;
            unsigned adj = ((unsigned)x & ((unsigned)x >> 1)) & 0x3FFFFu;
            int par = (__popc(adj) + ((x & 1) & ((x >> 18) & 1))) & 1;
            float s = par ? -1.0f : 1.0f;
            float2 a = amp[li];
            state[x] = make_float2(s * a.x, s * a.y);
        }
    } else {
        // Final layer: probs + expval partials. Measured qubits 0..7 are global
        // bits 18..11 == bits 7..0 of h.
        float ps[8];
#pragma unroll
        for (int w = 0; w < 8; ++w) ps[w] = 0.0f;
        for (int li = t; li < CHUNK; li += TPB) {
            float2 a = amp[li];
            float p = a.x * a.x + a.y * a.y;
            int h = li >> 3;
#pragma unroll
            for (int w = 0; w < 8; ++w) {
                ps[w] += ((h >> (7 - w)) & 1) ? -p : p;
            }
        }
        const int lane = t & 63, wid = t >> 6;
#pragma unroll
        for (int w = 0; w < 8; ++w) {
            float v = ps[w];
            for (int off = 32; off; off >>= 1) v += __shfl_down(v, off, 64);
            if (lane == 0) red[wid * 8 + w] = v;
        }
        __syncthreads();
        if (t < 8) {
            partials[T * 8 + t] = red[0 * 8 + t] + red[1 * 8 + t] +
                                  red[2 * 8 + t] + red[3 * 8 + t];
        }
    }
}

// Reduce 256 blocks x 8 outputs -> 8 outputs.
__global__ __launch_bounds__(TPB) void finalReduce(const float* __restrict__ partials,
                                                   float* __restrict__ out) {
    __shared__ float lds[TPB];
    const int t = threadIdx.x;
    float acc = 0.0f;
    for (int i = t; i < NBLK * 8; i += TPB) acc += partials[i];  // i%8 == t%8 invariant
    lds[t] = acc;
    __syncthreads();
    if (t < 8) {
        float s = 0.0f;
        for (int k = t; k < TPB; k += 8) s += lds[k];
        out[t] = s;
    }
}

extern "C" void kernel_launch(void* const* d_in, const int* in_sizes, int n_in,
                              void* d_out, int out_size, void* d_ws, size_t ws_size,
                              hipStream_t stream) {
    const float* inputs = (const float*)d_in[0];   // [19]
    const float* yw     = (const float*)d_in[1];   // [3,19]
    const float* zw     = (const float*)d_in[2];   // [3,19]
    float* out = (float*)d_out;                    // [8] float32

    float2* state   = (float2*)d_ws;                                   // 4 MB
    float* partials = (float*)((char*)d_ws + (size_t)NSTATE * sizeof(float2)); // 8 KB

    for (int l = 0; l < NL; ++l) {
        passA<<<NBLK, TPB, 0, stream>>>(inputs, yw, zw, state, l);
        passB<<<NBLK, TPB, 0, stream>>>(inputs, yw, zw, state, partials, l);
    }
    finalReduce<<<1, TPB, 0, stream>>>(partials, out);
}